// Round 11
// baseline (257.993 us; speedup 1.0000x reference)
//
#include <hip/hip_runtime.h>

// LowBitMixIn: out[b,o,t] = sum_{d=1..7} mixer[o,(o-d)&1023] * x[b, perm[(o-d)&1023], t]
// B=16, F=1024, T=4096, float32. Memory-bound streaming.
//
// R11: R10 structure (4 waves share rows -> 8KB block granule, LDS coefs,
// nt stores, pinned 4-deep prefetch) with OCH 32->16 so grid doubles to
// 2048 blocks = 32 waves/CU. Tests whether the 4.68 TB/s plateau is
// request-concurrency-limited. Cost: read amplification 22/16 (L3-absorbed).

#define F_DIM 1024
#define T_DIM 4096
#define T4 (T_DIM / 4)   // 1024 float4 per row
#define OCH 16           // o-rows per block (shared by all 4 waves)
#define PF 4             // prefetch distance (rows in flight)

typedef float fvec4 __attribute__((ext_vector_type(4)));

__global__ __launch_bounds__(256, 8) void lowbit_mix_kernel(
    const float* __restrict__ x, const float* __restrict__ mixer,
    const int* __restrict__ perm, float* __restrict__ out)
{
    __shared__ float sCoef[OCH][8];   // [row][d-1], d=1..8 (slot 8 unused zero)
    __shared__ int   sPerm[OCH + 8];  // perm[(block_o0 - 8 + j) & 1023]

    const int tid  = threadIdx.x;
    const int lane = tid & 63;
    const int w    = tid >> 6;                        // wave 0..3
    // block covers 512 t4 (8KB); wave w owns the 2KB stripe [w*128, w*128+128)
    const int t4   = blockIdx.x * 512 + w * 128 + lane;
    const int block_o0 = blockIdx.y * OCH;
    const int b    = blockIdx.z;

    // ---- stage coefs + perm into LDS (once per block) ----
    if (tid < OCH * 8) {
        const int r = tid >> 3;                       // 0..15
        const int d = (tid & 7) + 1;                  // 1..8
        const int o = block_o0 + r;
        sCoef[r][d - 1] = mixer[(size_t)o * F_DIM + ((o - d) & (F_DIM - 1))];
    }
    if (tid >= 128 && tid < 128 + OCH + 8) {
        const int j = tid - 128;
        sPerm[j] = perm[(block_o0 - 8 + j) & (F_DIM - 1)];
    }
    __syncthreads();

    const fvec4* __restrict__ xb =
        reinterpret_cast<const fvec4*>(x) + (size_t)b * F_DIM * T4;
    fvec4* __restrict__ ob =
        reinterpret_cast<fvec4*>(out) + (size_t)b * F_DIM * T4;

    // Rolling window: win[k][h] = x[input row o-7+k][t4 + 64h]
    fvec4 win[7][2];
#pragma unroll
    for (int k = 0; k < 7; ++k) {
        const size_t rowoff = (size_t)sPerm[1 + k] * T4 + t4;
        win[k][0] = xb[rowoff];
        win[k][1] = xb[rowoff + 64];
    }
    // Prefetch queue: pend[j] holds input row o0+j (consumed at iter j's end)
    fvec4 pend[PF][2];
#pragma unroll
    for (int j = 0; j < PF; ++j) {
        const size_t rowoff = (size_t)sPerm[8 + j] * T4 + t4;
        pend[j][0] = xb[rowoff];
        pend[j][1] = xb[rowoff + 64];
    }
    __builtin_amdgcn_sched_barrier(0);   // pin: prefetches issue here, not at use

#pragma unroll
    for (int oi = 0; oi < OCH; ++oi) {
        const int o = block_o0 + oi;                  // global output row

        fvec4 acc0 = (fvec4)(0.f);
        fvec4 acc1 = (fvec4)(0.f);
        // oldest (d=7) first ... newest (d=1) last
#pragma unroll
        for (int d = 7; d >= 1; --d) {
            const float c = sCoef[oi][d - 1];
            acc0 += c * win[7 - d][0];
            acc1 += c * win[7 - d][1];
        }
        const size_t ooff = (size_t)o * T4 + t4;
        __builtin_nontemporal_store(acc0, &ob[ooff]);
        __builtin_nontemporal_store(acc1, &ob[ooff + 64]);

        if (oi != OCH - 1) {
            // shift window; consume pend slot holding input row o0+oi
#pragma unroll
            for (int k = 0; k < 6; ++k) { win[k][0] = win[k + 1][0]; win[k][1] = win[k + 1][1]; }
            win[6][0] = pend[oi & (PF - 1)][0];
            win[6][1] = pend[oi & (PF - 1)][1];
            // refill slot with input row o0+oi+PF (last needed input is o0+OCH-2)
            if (oi + PF <= OCH - 2) {
                const size_t rowoff = (size_t)sPerm[8 + oi + PF] * T4 + t4;
                pend[oi & (PF - 1)][0] = xb[rowoff];
                pend[oi & (PF - 1)][1] = xb[rowoff + 64];
                __builtin_amdgcn_sched_barrier(0);  // pin issue point
            }
        }
    }
}

extern "C" void kernel_launch(void* const* d_in, const int* in_sizes, int n_in,
                              void* d_out, int out_size, void* d_ws, size_t ws_size,
                              hipStream_t stream) {
    const float* x     = (const float*)d_in[0];   // (16, 1024, 4096) f32
    const float* mixer = (const float*)d_in[1];   // (1024, 1024) f32
    const int*   perm  = (const int*)d_in[2];     // (1024,) i32
    float*       out   = (float*)d_out;           // (16, 1024, 4096) f32

    dim3 grid(T4 / 512,        // 2 t-chunks (block covers 512 t4 = 8KB)
              F_DIM / OCH,     // 64 o-tiles (16 rows, shared by 4 waves)
              16);             // batch  => 2048 blocks = 8/CU = 32 waves/CU
    dim3 block(256);
    lowbit_mix_kernel<<<grid, block, 0, stream>>>(x, mixer, perm, out);
}

// Round 12
// 94.935 us; speedup vs baseline: 2.7176x; 2.7176x over previous
//
#include <hip/hip_runtime.h>

// LowBitMixIn: out[b,o,t] = sum_{d=1..7} mixer[o,(o-d)&1023] * x[b, perm[(o-d)&1023], t]
// B=16, F=1024, T=4096, float32. Memory-bound streaming.
//
// R12: continue the fat-stream lever: 512-thread blocks (8 waves) where all
// waves share the same 32 rows and tile the FULL 16KB row. Each row access is
// one contiguous 16KB front at the memory controller. 512 blocks = 2/CU =
// 16 waves/CU (same as best R10, half the stream count). Per-wave code
// identical to R10: 2KB stripe, LDS coefs, nt stores, pinned PF=4.

#define F_DIM 1024
#define T_DIM 4096
#define T4 (T_DIM / 4)   // 1024 float4 per row
#define OCH 32           // o-rows per block (shared by all 8 waves)
#define PF 4             // prefetch distance (rows in flight)

typedef float fvec4 __attribute__((ext_vector_type(4)));

__global__ __launch_bounds__(512, 4) void lowbit_mix_kernel(
    const float* __restrict__ x, const float* __restrict__ mixer,
    const int* __restrict__ perm, float* __restrict__ out)
{
    __shared__ float sCoef[OCH][8];   // [row][d-1], d=1..8 (slot 8 unused zero)
    __shared__ int   sPerm[OCH + 8];  // perm[(block_o0 - 8 + j) & 1023]

    const int tid  = threadIdx.x;
    const int lane = tid & 63;
    const int w    = tid >> 6;                        // wave 0..7
    // block covers the FULL row (1024 t4 = 16KB); wave w owns stripe [w*128, w*128+128)
    const int t4   = w * 128 + lane;
    const int block_o0 = blockIdx.y * OCH;
    const int b    = blockIdx.z;

    // ---- stage coefs + perm into LDS (once per block) ----
    if (tid < OCH * 8) {
        const int r = tid >> 3;                       // 0..31
        const int d = (tid & 7) + 1;                  // 1..8
        const int o = block_o0 + r;
        sCoef[r][d - 1] = mixer[(size_t)o * F_DIM + ((o - d) & (F_DIM - 1))];
    }
    if (tid >= 256 && tid < 256 + OCH + 8) {
        const int j = tid - 256;
        sPerm[j] = perm[(block_o0 - 8 + j) & (F_DIM - 1)];
    }
    __syncthreads();

    const fvec4* __restrict__ xb =
        reinterpret_cast<const fvec4*>(x) + (size_t)b * F_DIM * T4;
    fvec4* __restrict__ ob =
        reinterpret_cast<fvec4*>(out) + (size_t)b * F_DIM * T4;

    // Rolling window: win[k][h] = x[input row o-7+k][t4 + 64h]
    fvec4 win[7][2];
#pragma unroll
    for (int k = 0; k < 7; ++k) {
        const size_t rowoff = (size_t)sPerm[1 + k] * T4 + t4;
        win[k][0] = xb[rowoff];
        win[k][1] = xb[rowoff + 64];
    }
    // Prefetch queue: pend[j] holds input row o0+j (consumed at iter j's end)
    fvec4 pend[PF][2];
#pragma unroll
    for (int j = 0; j < PF; ++j) {
        const size_t rowoff = (size_t)sPerm[8 + j] * T4 + t4;
        pend[j][0] = xb[rowoff];
        pend[j][1] = xb[rowoff + 64];
    }
    __builtin_amdgcn_sched_barrier(0);   // pin: prefetches issue here, not at use

#pragma unroll
    for (int oi = 0; oi < OCH; ++oi) {
        const int o = block_o0 + oi;                  // global output row

        fvec4 acc0 = (fvec4)(0.f);
        fvec4 acc1 = (fvec4)(0.f);
        // oldest (d=7) first ... newest (d=1) last
#pragma unroll
        for (int d = 7; d >= 1; --d) {
            const float c = sCoef[oi][d - 1];
            acc0 += c * win[7 - d][0];
            acc1 += c * win[7 - d][1];
        }
        const size_t ooff = (size_t)o * T4 + t4;
        __builtin_nontemporal_store(acc0, &ob[ooff]);
        __builtin_nontemporal_store(acc1, &ob[ooff + 64]);

        if (oi != OCH - 1) {
            // shift window; consume pend slot holding input row o0+oi
#pragma unroll
            for (int k = 0; k < 6; ++k) { win[k][0] = win[k + 1][0]; win[k][1] = win[k + 1][1]; }
            win[6][0] = pend[oi & (PF - 1)][0];
            win[6][1] = pend[oi & (PF - 1)][1];
            // refill slot with input row o0+oi+PF (last needed input is o0+OCH-2)
            if (oi + PF <= OCH - 2) {
                const size_t rowoff = (size_t)sPerm[8 + oi + PF] * T4 + t4;
                pend[oi & (PF - 1)][0] = xb[rowoff];
                pend[oi & (PF - 1)][1] = xb[rowoff + 64];
                __builtin_amdgcn_sched_barrier(0);  // pin issue point
            }
        }
    }
}

extern "C" void kernel_launch(void* const* d_in, const int* in_sizes, int n_in,
                              void* d_out, int out_size, void* d_ws, size_t ws_size,
                              hipStream_t stream) {
    const float* x     = (const float*)d_in[0];   // (16, 1024, 4096) f32
    const float* mixer = (const float*)d_in[1];   // (1024, 1024) f32
    const int*   perm  = (const int*)d_in[2];     // (1024,) i32
    float*       out   = (float*)d_out;           // (16, 1024, 4096) f32

    dim3 grid(1,               // full row per block (16KB front)
              F_DIM / OCH,     // 32 o-tiles (32 rows, shared by 8 waves)
              16);             // batch  => 512 blocks = 2/CU = 16 waves/CU
    dim3 block(512);
    lowbit_mix_kernel<<<grid, block, 0, stream>>>(x, mixer, perm, out);
}

// Round 13
// 90.288 us; speedup vs baseline: 2.8575x; 1.0515x over previous
//
#include <hip/hip_runtime.h>

// LowBitMixIn: out[b,o,t] = sum_{d=1..7} mixer[o,(o-d)&1023] * x[b, perm[(o-d)&1023], t]
// B=16, F=1024, T=4096, float32. Memory-bound streaming.
//
// R13: R10 (8KB block front, 4 waves share 32 rows, 2KB stripe/wave, LDS
// coefs, nt stores, PF=4) + asm keep-alives on win[] and pend[] each
// iteration. R9/R10 VGPR counts (40/56) prove the compiler was NOT keeping
// the 7-row window in registers (needs 56 alone) — it rematerialized loads,
// re-reading each row ~7x from L1/L2. 7 x 330MB / 89us ~ 33 TB/s = the L2
// aggregate ceiling -> kernel was L2-BW-bound. Forcing register residency
// cuts L2 read traffic ~7x.

#define F_DIM 1024
#define T_DIM 4096
#define T4 (T_DIM / 4)   // 1024 float4 per row
#define OCH 32           // o-rows per block (shared by all 4 waves)
#define PF 4             // prefetch distance (rows in flight)

typedef float fvec4 __attribute__((ext_vector_type(4)));

__global__ __launch_bounds__(256, 4) void lowbit_mix_kernel(
    const float* __restrict__ x, const float* __restrict__ mixer,
    const int* __restrict__ perm, float* __restrict__ out)
{
    __shared__ float sCoef[OCH][8];   // [row][d-1], d=1..8 (slot 8 unused zero)
    __shared__ int   sPerm[OCH + 8];  // perm[(block_o0 - 8 + j) & 1023]

    const int tid  = threadIdx.x;
    const int lane = tid & 63;
    const int w    = tid >> 6;                        // wave 0..3
    // block covers 512 t4 (8KB); wave w owns the 2KB stripe [w*128, w*128+128)
    const int t4   = blockIdx.x * 512 + w * 128 + lane;
    const int block_o0 = blockIdx.y * OCH;
    const int b    = blockIdx.z;

    // ---- stage coefs + perm into LDS (once per block) ----
    {
        const int r = tid >> 3;                       // 0..31
        const int d = (tid & 7) + 1;                  // 1..8
        const int o = block_o0 + r;
        sCoef[r][d - 1] = mixer[(size_t)o * F_DIM + ((o - d) & (F_DIM - 1))];
        if (tid < OCH + 8) {
            sPerm[tid] = perm[(block_o0 - 8 + tid) & (F_DIM - 1)];
        }
    }
    __syncthreads();

    const fvec4* __restrict__ xb =
        reinterpret_cast<const fvec4*>(x) + (size_t)b * F_DIM * T4;
    fvec4* __restrict__ ob =
        reinterpret_cast<fvec4*>(out) + (size_t)b * F_DIM * T4;

    // Rolling window: win[k][h] = x[input row o-7+k][t4 + 64h]
    fvec4 win[7][2];
#pragma unroll
    for (int k = 0; k < 7; ++k) {
        const size_t rowoff = (size_t)sPerm[1 + k] * T4 + t4;
        win[k][0] = xb[rowoff];
        win[k][1] = xb[rowoff + 64];
    }
    // Prefetch queue: pend[j] holds input row o0+j (consumed at iter j's end)
    fvec4 pend[PF][2];
#pragma unroll
    for (int j = 0; j < PF; ++j) {
        const size_t rowoff = (size_t)sPerm[8 + j] * T4 + t4;
        pend[j][0] = xb[rowoff];
        pend[j][1] = xb[rowoff + 64];
    }

#pragma unroll
    for (int oi = 0; oi < OCH; ++oi) {
        const int o = block_o0 + oi;                  // global output row

        // Force window + prefetch queue to be REGISTER-RESIDENT across the
        // iteration (defeats load rematerialization / sinking).
        asm volatile("" : "+v"(win[0][0]), "+v"(win[1][0]), "+v"(win[2][0]),
                          "+v"(win[3][0]), "+v"(win[4][0]), "+v"(win[5][0]),
                          "+v"(win[6][0]));
        asm volatile("" : "+v"(win[0][1]), "+v"(win[1][1]), "+v"(win[2][1]),
                          "+v"(win[3][1]), "+v"(win[4][1]), "+v"(win[5][1]),
                          "+v"(win[6][1]));
        asm volatile("" : "+v"(pend[0][0]), "+v"(pend[1][0]),
                          "+v"(pend[2][0]), "+v"(pend[3][0]));
        asm volatile("" : "+v"(pend[0][1]), "+v"(pend[1][1]),
                          "+v"(pend[2][1]), "+v"(pend[3][1]));

        fvec4 acc0 = (fvec4)(0.f);
        fvec4 acc1 = (fvec4)(0.f);
        // oldest (d=7) first ... newest (d=1) last
#pragma unroll
        for (int d = 7; d >= 1; --d) {
            const float c = sCoef[oi][d - 1];
            acc0 += c * win[7 - d][0];
            acc1 += c * win[7 - d][1];
        }
        const size_t ooff = (size_t)o * T4 + t4;
        __builtin_nontemporal_store(acc0, &ob[ooff]);
        __builtin_nontemporal_store(acc1, &ob[ooff + 64]);

        if (oi != OCH - 1) {
            // shift window; consume pend slot holding input row o0+oi
#pragma unroll
            for (int k = 0; k < 6; ++k) { win[k][0] = win[k + 1][0]; win[k][1] = win[k + 1][1]; }
            win[6][0] = pend[oi & (PF - 1)][0];
            win[6][1] = pend[oi & (PF - 1)][1];
            // refill slot with input row o0+oi+PF (last needed input is o0+OCH-2)
            if (oi + PF <= OCH - 2) {
                const size_t rowoff = (size_t)sPerm[8 + oi + PF] * T4 + t4;
                pend[oi & (PF - 1)][0] = xb[rowoff];
                pend[oi & (PF - 1)][1] = xb[rowoff + 64];
            }
        }
    }
}

extern "C" void kernel_launch(void* const* d_in, const int* in_sizes, int n_in,
                              void* d_out, int out_size, void* d_ws, size_t ws_size,
                              hipStream_t stream) {
    const float* x     = (const float*)d_in[0];   // (16, 1024, 4096) f32
    const float* mixer = (const float*)d_in[1];   // (1024, 1024) f32
    const int*   perm  = (const int*)d_in[2];     // (1024,) i32
    float*       out   = (float*)d_out;           // (16, 1024, 4096) f32

    dim3 grid(T4 / 512,        // 2 t-chunks (block covers 512 t4 = 8KB)
              F_DIM / OCH,     // 32 o-tiles (32 rows, shared by 4 waves)
              16);             // batch  => 1024 blocks = 4/CU = 16 waves/CU
    dim3 block(256);
    lowbit_mix_kernel<<<grid, block, 0, stream>>>(x, mixer, perm, out);
}

// Round 14
// 83.720 us; speedup vs baseline: 3.0816x; 1.0784x over previous
//
#include <hip/hip_runtime.h>

// LowBitMixIn: out[b,o,t] = sum_{d=1..7} mixer[o,(o-d)&1023] * x[b, perm[(o-d)&1023], t]
// B=16, F=1024, T=4096, float32. Memory-bound streaming.
//
// R14: R10 per-wave structure (8KB block front, 4 waves share rows, 2KB
// stripe/wave, LDS coefs, nt stores, PF=4) with OCH 32->64: each block sweeps
// 64 rows so window boundary re-reads drop from 6/32 to 6/64 of the stream
// (amplification 1.19 -> 1.09, logical fabric traffic -4.3%). Grid 512 blocks.

#define F_DIM 1024
#define T_DIM 4096
#define T4 (T_DIM / 4)   // 1024 float4 per row
#define OCH 64           // o-rows per block (shared by all 4 waves)
#define PF 4             // prefetch distance (rows in flight)

typedef float fvec4 __attribute__((ext_vector_type(4)));

__global__ __launch_bounds__(256, 4) void lowbit_mix_kernel(
    const float* __restrict__ x, const float* __restrict__ mixer,
    const int* __restrict__ perm, float* __restrict__ out)
{
    __shared__ float sCoef[OCH][8];   // [row][d-1], d=1..8 (slot 8 unused zero)
    __shared__ int   sPerm[OCH + 8];  // perm[(block_o0 - 8 + j) & 1023]

    const int tid  = threadIdx.x;
    const int lane = tid & 63;
    const int w    = tid >> 6;                        // wave 0..3
    // block covers 512 t4 (8KB); wave w owns the 2KB stripe [w*128, w*128+128)
    const int t4   = blockIdx.x * 512 + w * 128 + lane;
    const int block_o0 = blockIdx.y * OCH;
    const int b    = blockIdx.z;

    // ---- stage coefs + perm into LDS (once per block) ----
#pragma unroll
    for (int idx = tid; idx < OCH * 8; idx += 256) {
        const int r = idx >> 3;                       // 0..63
        const int d = (idx & 7) + 1;                  // 1..8
        const int o = block_o0 + r;
        sCoef[r][d - 1] = mixer[(size_t)o * F_DIM + ((o - d) & (F_DIM - 1))];
    }
    if (tid < OCH + 8) {
        sPerm[tid] = perm[(block_o0 - 8 + tid) & (F_DIM - 1)];
    }
    __syncthreads();

    const fvec4* __restrict__ xb =
        reinterpret_cast<const fvec4*>(x) + (size_t)b * F_DIM * T4;
    fvec4* __restrict__ ob =
        reinterpret_cast<fvec4*>(out) + (size_t)b * F_DIM * T4;

    // Rolling window: win[k][h] = x[input row o-7+k][t4 + 64h]
    fvec4 win[7][2];
#pragma unroll
    for (int k = 0; k < 7; ++k) {
        const size_t rowoff = (size_t)sPerm[1 + k] * T4 + t4;
        win[k][0] = xb[rowoff];
        win[k][1] = xb[rowoff + 64];
    }
    // Prefetch queue: pend[j] holds input row o0+j (consumed at iter j's end)
    fvec4 pend[PF][2];
#pragma unroll
    for (int j = 0; j < PF; ++j) {
        const size_t rowoff = (size_t)sPerm[8 + j] * T4 + t4;
        pend[j][0] = xb[rowoff];
        pend[j][1] = xb[rowoff + 64];
    }
    __builtin_amdgcn_sched_barrier(0);   // pin: prefetches issue here, not at use

#pragma unroll
    for (int oi = 0; oi < OCH; ++oi) {
        const int o = block_o0 + oi;                  // global output row

        fvec4 acc0 = (fvec4)(0.f);
        fvec4 acc1 = (fvec4)(0.f);
        // oldest (d=7) first ... newest (d=1) last
#pragma unroll
        for (int d = 7; d >= 1; --d) {
            const float c = sCoef[oi][d - 1];
            acc0 += c * win[7 - d][0];
            acc1 += c * win[7 - d][1];
        }
        const size_t ooff = (size_t)o * T4 + t4;
        __builtin_nontemporal_store(acc0, &ob[ooff]);
        __builtin_nontemporal_store(acc1, &ob[ooff + 64]);

        if (oi != OCH - 1) {
            // shift window; consume pend slot holding input row o0+oi
#pragma unroll
            for (int k = 0; k < 6; ++k) { win[k][0] = win[k + 1][0]; win[k][1] = win[k + 1][1]; }
            win[6][0] = pend[oi & (PF - 1)][0];
            win[6][1] = pend[oi & (PF - 1)][1];
            // refill slot with input row o0+oi+PF (last needed input is o0+OCH-2)
            if (oi + PF <= OCH - 2) {
                const size_t rowoff = (size_t)sPerm[8 + oi + PF] * T4 + t4;
                pend[oi & (PF - 1)][0] = xb[rowoff];
                pend[oi & (PF - 1)][1] = xb[rowoff + 64];
                __builtin_amdgcn_sched_barrier(0);  // pin issue point
            }
        }
    }
}

extern "C" void kernel_launch(void* const* d_in, const int* in_sizes, int n_in,
                              void* d_out, int out_size, void* d_ws, size_t ws_size,
                              hipStream_t stream) {
    const float* x     = (const float*)d_in[0];   // (16, 1024, 4096) f32
    const float* mixer = (const float*)d_in[1];   // (1024, 1024) f32
    const int*   perm  = (const int*)d_in[2];     // (1024,) i32
    float*       out   = (float*)d_out;           // (16, 1024, 4096) f32

    dim3 grid(T4 / 512,        // 2 t-chunks (block covers 512 t4 = 8KB)
              F_DIM / OCH,     // 16 o-tiles (64 rows, shared by 4 waves)
              16);             // batch  => 512 blocks = 2/CU = 8 waves/CU
    dim3 block(256);
    lowbit_mix_kernel<<<grid, block, 0, stream>>>(x, mixer, perm, out);
}

// Round 15
// 82.236 us; speedup vs baseline: 3.1372x; 1.0181x over previous
//
#include <hip/hip_runtime.h>

// LowBitMixIn: out[b,o,t] = sum_{d=1..7} mixer[o,(o-d)&1023] * x[b, perm[(o-d)&1023], t]
// B=16, F=1024, T=4096, float32. Memory-bound streaming.
//
// R15: final step of the fewer/fatter/less-amplified-streams lever:
// OCH 64->128 (amplification 1.094 -> 1.047), 256 blocks = 1/CU.
// Everything else identical to R14 (8KB block front, 4 waves share rows,
// 2KB stripe/wave, LDS coefs, nt stores, pinned PF=4).

#define F_DIM 1024
#define T_DIM 4096
#define T4 (T_DIM / 4)   // 1024 float4 per row
#define OCH 128          // o-rows per block (shared by all 4 waves)
#define PF 4             // prefetch distance (rows in flight)

typedef float fvec4 __attribute__((ext_vector_type(4)));

__global__ __launch_bounds__(256, 4) void lowbit_mix_kernel(
    const float* __restrict__ x, const float* __restrict__ mixer,
    const int* __restrict__ perm, float* __restrict__ out)
{
    __shared__ float sCoef[OCH][8];   // [row][d-1], d=1..8 (slot 8 unused zero)
    __shared__ int   sPerm[OCH + 8];  // perm[(block_o0 - 8 + j) & 1023]

    const int tid  = threadIdx.x;
    const int lane = tid & 63;
    const int w    = tid >> 6;                        // wave 0..3
    // block covers 512 t4 (8KB); wave w owns the 2KB stripe [w*128, w*128+128)
    const int t4   = blockIdx.x * 512 + w * 128 + lane;
    const int block_o0 = blockIdx.y * OCH;
    const int b    = blockIdx.z;

    // ---- stage coefs + perm into LDS (once per block) ----
#pragma unroll
    for (int idx = tid; idx < OCH * 8; idx += 256) {
        const int r = idx >> 3;                       // 0..127
        const int d = (idx & 7) + 1;                  // 1..8
        const int o = block_o0 + r;
        sCoef[r][d - 1] = mixer[(size_t)o * F_DIM + ((o - d) & (F_DIM - 1))];
    }
    if (tid < OCH + 8) {
        sPerm[tid] = perm[(block_o0 - 8 + tid) & (F_DIM - 1)];
    }
    __syncthreads();

    const fvec4* __restrict__ xb =
        reinterpret_cast<const fvec4*>(x) + (size_t)b * F_DIM * T4;
    fvec4* __restrict__ ob =
        reinterpret_cast<fvec4*>(out) + (size_t)b * F_DIM * T4;

    // Rolling window: win[k][h] = x[input row o-7+k][t4 + 64h]
    fvec4 win[7][2];
#pragma unroll
    for (int k = 0; k < 7; ++k) {
        const size_t rowoff = (size_t)sPerm[1 + k] * T4 + t4;
        win[k][0] = xb[rowoff];
        win[k][1] = xb[rowoff + 64];
    }
    // Prefetch queue: pend[j] holds input row o0+j (consumed at iter j's end)
    fvec4 pend[PF][2];
#pragma unroll
    for (int j = 0; j < PF; ++j) {
        const size_t rowoff = (size_t)sPerm[8 + j] * T4 + t4;
        pend[j][0] = xb[rowoff];
        pend[j][1] = xb[rowoff + 64];
    }
    __builtin_amdgcn_sched_barrier(0);   // pin: prefetches issue here, not at use

#pragma unroll
    for (int oi = 0; oi < OCH; ++oi) {
        const int o = block_o0 + oi;                  // global output row

        fvec4 acc0 = (fvec4)(0.f);
        fvec4 acc1 = (fvec4)(0.f);
        // oldest (d=7) first ... newest (d=1) last
#pragma unroll
        for (int d = 7; d >= 1; --d) {
            const float c = sCoef[oi][d - 1];
            acc0 += c * win[7 - d][0];
            acc1 += c * win[7 - d][1];
        }
        const size_t ooff = (size_t)o * T4 + t4;
        __builtin_nontemporal_store(acc0, &ob[ooff]);
        __builtin_nontemporal_store(acc1, &ob[ooff + 64]);

        if (oi != OCH - 1) {
            // shift window; consume pend slot holding input row o0+oi
#pragma unroll
            for (int k = 0; k < 6; ++k) { win[k][0] = win[k + 1][0]; win[k][1] = win[k + 1][1]; }
            win[6][0] = pend[oi & (PF - 1)][0];
            win[6][1] = pend[oi & (PF - 1)][1];
            // refill slot with input row o0+oi+PF (last needed input is o0+OCH-2)
            if (oi + PF <= OCH - 2) {
                const size_t rowoff = (size_t)sPerm[8 + oi + PF] * T4 + t4;
                pend[oi & (PF - 1)][0] = xb[rowoff];
                pend[oi & (PF - 1)][1] = xb[rowoff + 64];
                __builtin_amdgcn_sched_barrier(0);  // pin issue point
            }
        }
    }
}

extern "C" void kernel_launch(void* const* d_in, const int* in_sizes, int n_in,
                              void* d_out, int out_size, void* d_ws, size_t ws_size,
                              hipStream_t stream) {
    const float* x     = (const float*)d_in[0];   // (16, 1024, 4096) f32
    const float* mixer = (const float*)d_in[1];   // (1024, 1024) f32
    const int*   perm  = (const int*)d_in[2];     // (1024,) i32
    float*       out   = (float*)d_out;           // (16, 1024, 4096) f32

    dim3 grid(T4 / 512,        // 2 t-chunks (block covers 512 t4 = 8KB)
              F_DIM / OCH,     // 8 o-tiles (128 rows, shared by 4 waves)
              16);             // batch  => 256 blocks = 1/CU = 4 waves/CU
    dim3 block(256);
    lowbit_mix_kernel<<<grid, block, 0, stream>>>(x, mixer, perm, out);
}